// Round 1
// baseline (15929.407 us; speedup 1.0000x reference)
//
#include <hip/hip_runtime.h>
#include <math.h>

#define NTHREADS 256
#define NBLOCKS  256
#define TSTEPS   1024
#define BATCH    64
#define CDIM     512

typedef __attribute__((ext_vector_type(8))) short short8;
typedef __attribute__((ext_vector_type(8))) unsigned short ushort8;
typedef __attribute__((ext_vector_type(4))) float f32x4;

// ---- dynamic LDS layout (bytes) ----
#define WIH_OFF 0                     // 32 rows x 512 bf16 = 32768
#define WHH_OFF (WIH_OFF + 32768)     // 32768
#define XA_OFF  (WHH_OFF + 32768)     // 16 x 512 bf16 = 16384
#define HA_OFF  (XA_OFF + 16384)      // 16384
#define XG_OFF  (HA_OFF + 16384)      // 2 * 16*33 f32 = 4224
#define GB_OFF  (XG_OFF + 4224)       // 16*33 f32 = 2112
#define CB_OFF  (GB_OFF + 2112)       // 128 f32 = 512
#define BIAS_OFF (CB_OFF + 512)       // 32 f32 = 128
#define SMEM_BYTES (BIAS_OFF + 128)   // 105280 B < 160 KiB

// ws layout: h exchange [2][4][16][512] bf16 = 131072 B, then 256 u32 flags
#define HEX_BYTES 131072

__device__ __forceinline__ unsigned short f2bf(float x) {
  unsigned u = __builtin_bit_cast(unsigned, x);
  unsigned r = (u + 0x7FFFu + ((u >> 16) & 1u)) >> 16;
  return (unsigned short)r;
}

__device__ __forceinline__ float sigm(float z) { return 1.0f / (1.0f + expf(-z)); }

// reset may arrive as i32 (mode 0), u8 (1), f32 (2), or i64 (3)
__device__ __forceinline__ float keepf(const void* rst, int mode, int idx) {
  bool r;
  if (mode == 0)      r = ((const int*)rst)[idx] != 0;
  else if (mode == 1) r = ((const unsigned char*)rst)[idx] != 0;
  else if (mode == 2) r = ((const float*)rst)[idx] != 0.0f;
  else                r = ((const int*)rst)[2 * idx] != 0;  // i64 little-endian low word
  return r ? 0.0f : 1.0f;
}

// One 16x16 output tile over K=512: A rows from LDS tile at aoff (16 rows x 1KB,
// XOR-swizzled), B rows (= W[n][k], i.e. B^T layout) from LDS at woff, rows brow0..brow0+15.
__device__ __forceinline__ f32x4 tile_gemm(const char* smem, int aoff, int woff,
                                           int brow0, int lane) {
  const int grp = lane >> 4, r = lane & 15;
  f32x4 acc = {0.f, 0.f, 0.f, 0.f};
#pragma unroll
  for (int kk = 0; kk < 16; ++kk) {
    const int ab = aoff + r * 1024 + ((kk * 64 + grp * 16) ^ ((r & 7) << 4));
    const int brow = brow0 + r;
    const int bb = woff + brow * 1024 + ((kk * 64 + grp * 16) ^ ((brow & 7) << 4));
    short8 a = *(const short8*)(smem + ab);
    short8 b = *(const short8*)(smem + bb);
    acc = __builtin_amdgcn_mfma_f32_16x16x32_bf16(a, b, acc, 0, 0, 0);
  }
  return acc;
}

__global__ __launch_bounds__(NTHREADS, 1) void rlstm_persistent(
    const float* __restrict__ x, const void* __restrict__ rst,
    const float* __restrict__ h0, const float* __restrict__ c0,
    const float* __restrict__ wih, const float* __restrict__ whh,
    const float* __restrict__ bih, const float* __restrict__ bhh,
    float* __restrict__ y, unsigned short* __restrict__ hex,
    unsigned* __restrict__ flags) {
  extern __shared__ __align__(16) char smem[];
  float* XGf = (float*)(smem + XG_OFF);    // [2][16*33]
  float* GBf = (float*)(smem + GB_OFF);    // [16*33]
  float* CBf = (float*)(smem + CB_OFF);    // [128]
  float* BIASf = (float*)(smem + BIAS_OFF);

  const int tid = threadIdx.x;
  const int bid = blockIdx.x;
  const int bg = bid & 3;    // batch group: 16 batches
  const int cg = bid >> 2;   // column group: 8 c-indices -> 32 gate rows
  const int lane = tid & 63;

  // ---- detect reset dtype from bit patterns of first 4KB ----
  __shared__ int s_oki, s_okf, s_oddnz;
  if (tid == 0) { s_oki = 1; s_okf = 1; s_oddnz = 0; }
  __syncthreads();
  {
    int oki = 1, okf = 1, oddnz = 0;
    for (int i = tid; i < 1024; i += NTHREADS) {
      unsigned v = ((const unsigned*)rst)[i];
      oki &= (v <= 1u);
      okf &= (v == 0u || v == 0x3F800000u);
      if ((i & 1) && v != 0u) oddnz = 1;
    }
    if (!oki) atomicAnd(&s_oki, 0);
    if (!okf) atomicAnd(&s_okf, 0);
    if (oddnz) atomicOr(&s_oddnz, 1);
  }

  // ---- stage W_ih, W_hh slices (32 rows x 512) to LDS as bf16, swizzled ----
  for (int mtx = 0; mtx < 2; ++mtx) {
    const float* W = mtx ? whh : wih;
    const int base = mtx ? WHH_OFF : WIH_OFF;
    for (int it = 0; it < 8; ++it) {
      int idx = tid + it * NTHREADS;  // 0..2047
      int row = idx >> 6;             // 0..31
      int g = idx & 63;
      int grow = (row >> 3) * CDIM + cg * 8 + (row & 7);
      const float* s = W + (size_t)grow * CDIM + g * 8;
      float4 lo = *(const float4*)s;
      float4 hi = *(const float4*)(s + 4);
      short8 fr;
      fr[0] = (short)f2bf(lo.x); fr[1] = (short)f2bf(lo.y);
      fr[2] = (short)f2bf(lo.z); fr[3] = (short)f2bf(lo.w);
      fr[4] = (short)f2bf(hi.x); fr[5] = (short)f2bf(hi.y);
      fr[6] = (short)f2bf(hi.z); fr[7] = (short)f2bf(hi.w);
      *(short8*)(smem + base + row * 1024 + ((g * 16) ^ ((row & 7) << 4))) = fr;
    }
  }
  if (tid < 32) {
    int grow = (tid >> 3) * CDIM + cg * 8 + (tid & 7);
    BIASf[tid] = bih[grow] + bhh[grow];
  }
  __syncthreads();
  const int mode = s_oki ? (s_oddnz ? 0 : 3) : (s_okf ? 2 : 1);

  // ---- prologue: stage x[0], compute xg[0] ----
  if (tid >= 128) {
    const int u = tid - 128;
    for (int it = 0; it < 8; ++it) {
      int idx = u + it * 128; int row = idx >> 6; int g = idx & 63;
      const float* s = x + (size_t)(bg * 16 + row) * CDIM + g * 8;
      float4 lo = *(const float4*)s; float4 hi = *(const float4*)(s + 4);
      short8 fr;
      fr[0] = (short)f2bf(lo.x); fr[1] = (short)f2bf(lo.y);
      fr[2] = (short)f2bf(lo.z); fr[3] = (short)f2bf(lo.w);
      fr[4] = (short)f2bf(hi.x); fr[5] = (short)f2bf(hi.y);
      fr[6] = (short)f2bf(hi.z); fr[7] = (short)f2bf(hi.w);
      *(short8*)(smem + XA_OFF + row * 1024 + ((g * 16) ^ ((row & 7) << 4))) = fr;
    }
  }
  __syncthreads();
  if (tid >= 128) {
    int w = (tid >> 6) - 2;
    f32x4 acc = tile_gemm(smem, XA_OFF, WIH_OFF, w * 16, lane);
    const int grp = lane >> 4, r = lane & 15;
#pragma unroll
    for (int q = 0; q < 4; ++q) {
      int m = grp * 4 + q, n = w * 16 + r;
      XGf[m * 33 + n] = acc[q] + BIASf[n];
    }
  }
  __syncthreads();

  // ---- main sequential loop ----
  for (int t = 0; t < TSTEPS; ++t) {
    const int pcur = t & 1, pnext = pcur ^ 1;

    if (tid < 128) {
      if (t > 0) {
        const int fidx = bg + 4 * lane;  // the 64 blocks of this batch group
        const unsigned tgt = (unsigned)t;
        while (true) {
          unsigned v = __hip_atomic_load(&flags[fidx], __ATOMIC_RELAXED,
                                         __HIP_MEMORY_SCOPE_AGENT);
          if (__all((int)(v >= tgt))) break;
          __builtin_amdgcn_s_sleep(1);
        }
        __builtin_amdgcn_fence(__ATOMIC_ACQUIRE, "agent");
      }
      // stage (masked) h into HA
      const unsigned short* hsrc = hex + ((size_t)pnext * 4 + bg) * 8192;
      for (int it = 0; it < 8; ++it) {
        int idx = tid + it * 128; int row = idx >> 6; int g = idx & 63;
        float kp = keepf(rst, mode, t * BATCH + bg * 16 + row);
        short8 fr;
        if (t == 0) {
          const float* s = h0 + (size_t)(bg * 16 + row) * CDIM + g * 8;
          float4 lo = *(const float4*)s; float4 hi = *(const float4*)(s + 4);
          fr[0] = (short)f2bf(lo.x * kp); fr[1] = (short)f2bf(lo.y * kp);
          fr[2] = (short)f2bf(lo.z * kp); fr[3] = (short)f2bf(lo.w * kp);
          fr[4] = (short)f2bf(hi.x * kp); fr[5] = (short)f2bf(hi.y * kp);
          fr[6] = (short)f2bf(hi.z * kp); fr[7] = (short)f2bf(hi.w * kp);
        } else {
          ushort8 v = *(const ushort8*)(hsrc + (size_t)row * 512 + g * 8);
          fr = __builtin_bit_cast(short8, v);
          if (kp == 0.0f) fr = (short8)(short)0;
        }
        *(short8*)(smem + HA_OFF + row * 1024 + ((g * 16) ^ ((row & 7) << 4))) = fr;
      }
    } else if (t + 1 < TSTEPS) {
      // stage x[t+1]
      const int u = tid - 128;
      for (int it = 0; it < 8; ++it) {
        int idx = u + it * 128; int row = idx >> 6; int g = idx & 63;
        const float* s = x + ((size_t)(t + 1) * BATCH + bg * 16 + row) * CDIM + g * 8;
        float4 lo = *(const float4*)s; float4 hi = *(const float4*)(s + 4);
        short8 fr;
        fr[0] = (short)f2bf(lo.x); fr[1] = (short)f2bf(lo.y);
        fr[2] = (short)f2bf(lo.z); fr[3] = (short)f2bf(lo.w);
        fr[4] = (short)f2bf(hi.x); fr[5] = (short)f2bf(hi.y);
        fr[6] = (short)f2bf(hi.z); fr[7] = (short)f2bf(hi.w);
        *(short8*)(smem + XA_OFF + row * 1024 + ((g * 16) ^ ((row & 7) << 4))) = fr;
      }
    }
    __syncthreads();  // #1

    const int w = tid >> 6;
    const int grp = lane >> 4, r = lane & 15;
    if (w < 2) {
      // recurrent GEMM for step t
      f32x4 acc = tile_gemm(smem, HA_OFF, WHH_OFF, w * 16, lane);
#pragma unroll
      for (int q = 0; q < 4; ++q) {
        int m = grp * 4 + q, n = w * 16 + r;
        GBf[m * 33 + n] = acc[q] + XGf[pcur * 528 + m * 33 + n];
      }
    } else if (t + 1 < TSTEPS) {
      // x projection for step t+1
      f32x4 acc = tile_gemm(smem, XA_OFF, WIH_OFF, (w - 2) * 16, lane);
#pragma unroll
      for (int q = 0; q < 4; ++q) {
        int m = grp * 4 + q, n = (w - 2) * 16 + r;
        XGf[pnext * 528 + m * 33 + n] = acc[q] + BIASf[n];
      }
    }
    __syncthreads();  // #2

    if (tid < 128) {
      const int m = tid >> 3, jj = tid & 7;
      float kp = keepf(rst, mode, t * BATCH + bg * 16 + m);
      float cprev =
          (t == 0 ? c0[(size_t)(bg * 16 + m) * CDIM + cg * 8 + jj] : CBf[tid]) * kp;
      float gi = GBf[m * 33 + jj];
      float gf = GBf[m * 33 + 8 + jj];
      float gg = GBf[m * 33 + 16 + jj];
      float go = GBf[m * 33 + 24 + jj];
      float cnew = sigm(gf) * cprev + sigm(gi) * tanhf(gg);
      float hnew = sigm(go) * tanhf(cnew);
      CBf[tid] = cnew;
      __builtin_nontemporal_store(
          hnew, &y[((size_t)t * BATCH + bg * 16 + m) * CDIM + cg * 8 + jj]);
      hex[((size_t)pcur * 4 + bg) * 8192 + (size_t)m * 512 + cg * 8 + jj] = f2bf(hnew);
    }
    __syncthreads();  // #3 (drains all vmem stores to L2)

    if (tid == 0) {
      __builtin_amdgcn_fence(__ATOMIC_RELEASE, "agent");  // wb L2 -> coherence point
      __hip_atomic_store(&flags[bid], (unsigned)(t + 1), __ATOMIC_RELAXED,
                         __HIP_MEMORY_SCOPE_AGENT);
    }
  }
}

extern "C" void kernel_launch(void* const* d_in, const int* in_sizes, int n_in,
                              void* d_out, int out_size, void* d_ws, size_t ws_size,
                              hipStream_t stream) {
  (void)in_sizes; (void)n_in; (void)out_size; (void)ws_size;
  const float* x = (const float*)d_in[0];
  const void* rst = d_in[1];
  const float* h0 = (const float*)d_in[2];
  const float* c0 = (const float*)d_in[3];
  const float* wih = (const float*)d_in[4];
  const float* whh = (const float*)d_in[5];
  const float* bih = (const float*)d_in[6];
  const float* bhh = (const float*)d_in[7];
  float* y = (float*)d_out;
  unsigned short* hex = (unsigned short*)d_ws;
  unsigned* flags = (unsigned*)((char*)d_ws + HEX_BYTES);

  hipMemsetAsync((char*)d_ws + HEX_BYTES, 0, NBLOCKS * sizeof(unsigned), stream);

  hipFuncSetAttribute(reinterpret_cast<const void*>(rlstm_persistent),
                      hipFuncAttributeMaxDynamicSharedMemorySize, SMEM_BYTES);

  void* args[] = {(void*)&x,   (void*)&rst, (void*)&h0,  (void*)&c0,
                  (void*)&wih, (void*)&whh, (void*)&bih, (void*)&bhh,
                  (void*)&y,   (void*)&hex, (void*)&flags};
  hipLaunchCooperativeKernel((void*)rlstm_persistent, dim3(NBLOCKS), dim3(NTHREADS),
                             args, SMEM_BYTES, stream);
}

// Round 3
// 7465.615 us; speedup vs baseline: 2.1337x; 2.1337x over previous
//
#include <hip/hip_runtime.h>
#include <math.h>

#define NTHREADS 256
#define NBLOCKS  256
#define TSTEPS   1024
#define BATCH    64
#define CDIM     512

typedef __attribute__((ext_vector_type(8))) short short8;
typedef __attribute__((ext_vector_type(4))) float f32x4;
typedef __attribute__((ext_vector_type(2))) float f32x2;

// ---- dynamic LDS layout (bytes) ----
// XA: staged x tile, 16 rows x 512 bf16 (swizzled) = 16384
// XG: xg double buffer, 2 * 16*33 f32 = 4224
// GB: gate buffer, 16*33 f32 = 2112
// CB: c state, 128 f32 = 512
// BIAS: 32 f32 = 128
#define XA_OFF   0
#define XG_OFF   16384
#define GB_OFF   (XG_OFF + 4224)
#define CB_OFF   (GB_OFF + 2112)
#define BIAS_OFF (CB_OFF + 512)
// pad dynamic LDS to force 1 block/CU (2*98304 > 163840) -> full VGPR budget,
// and exactly 256 co-resident blocks under cooperative launch.
#define SMEM_BYTES 98304

// ws: h exchange [2][4][16][512] bf16 = 131072 B, then 256 u32 flags
#define HEX_BYTES 131072

__device__ __forceinline__ unsigned short f2bf(float x) {
  unsigned u = __builtin_bit_cast(unsigned, x);
  unsigned r = (u + 0x7FFFu + ((u >> 16) & 1u)) >> 16;
  return (unsigned short)r;
}

__device__ __forceinline__ short8 pack8(float4 lo, float4 hi) {
  short8 r;
  r[0] = (short)f2bf(lo.x); r[1] = (short)f2bf(lo.y);
  r[2] = (short)f2bf(lo.z); r[3] = (short)f2bf(lo.w);
  r[4] = (short)f2bf(hi.x); r[5] = (short)f2bf(hi.y);
  r[6] = (short)f2bf(hi.z); r[7] = (short)f2bf(hi.w);
  return r;
}

__device__ __forceinline__ float sigm(float z) { return 1.0f / (1.0f + expf(-z)); }

// reset may arrive as i32 (mode 0), u8 (1), f32 (2), or i64 (3)
__device__ __forceinline__ float keepf(const void* rst, int mode, int idx) {
  bool r;
  if (mode == 0)      r = ((const int*)rst)[idx] != 0;
  else if (mode == 1) r = ((const unsigned char*)rst)[idx] != 0;
  else if (mode == 2) r = ((const float*)rst)[idx] != 0.0f;
  else                r = ((const int*)rst)[2 * idx] != 0;  // i64 low word
  return r ? 0.0f : 1.0f;
}

// stage x[t] tile (16 rows x 512) into XA as swizzled bf16; threads 128..255
__device__ __forceinline__ void stage_x(char* smem, const float* x, int t, int bg,
                                        int tid) {
  const int u = tid - 128;
  for (int it = 0; it < 8; ++it) {
    int idx = u + it * 128; int row = idx >> 6; int g = idx & 63;
    const float* s = x + ((size_t)t * BATCH + bg * 16 + row) * CDIM + g * 8;
    float4 lo = *(const float4*)s; float4 hi = *(const float4*)(s + 4);
    *(short8*)(smem + XA_OFF + row * 1024 + ((g * 16) ^ ((row & 7) << 4))) =
        pack8(lo, hi);
  }
}

__global__ __launch_bounds__(NTHREADS, 1) void rlstm_persistent(
    const float* __restrict__ x, const void* __restrict__ rst,
    const float* __restrict__ h0, const float* __restrict__ c0,
    const float* __restrict__ wih, const float* __restrict__ whh,
    const float* __restrict__ bih, const float* __restrict__ bhh,
    float* __restrict__ y, unsigned short* __restrict__ hex,
    unsigned* __restrict__ flags) {
  extern __shared__ __align__(16) char smem[];
  float* XGf = (float*)(smem + XG_OFF);    // [2][16*33]
  float* GBf = (float*)(smem + GB_OFF);    // [16*33]
  float* CBf = (float*)(smem + CB_OFF);    // [128]
  float* BIASf = (float*)(smem + BIAS_OFF);

  const int tid = threadIdx.x;
  const int bid = blockIdx.x;
  const int bg = bid & 3;    // batch group: 16 batches
  const int cg = bid >> 2;   // column group: 8 c-indices -> 32 gate rows
  const int lane = tid & 63;
  const int wv = tid >> 6;           // wave 0..3
  const int grp = lane >> 4;         // k-group within fragment
  const int lr = lane & 15;          // row (A) / col (B) within fragment

  // ---- detect reset dtype from bit patterns of first 4KB ----
  __shared__ int s_oki, s_okf, s_oddnz;
  if (tid == 0) { s_oki = 1; s_okf = 1; s_oddnz = 0; }
  __syncthreads();
  {
    int oki = 1, okf = 1, oddnz = 0;
    for (int i = tid; i < 1024; i += NTHREADS) {
      unsigned v = ((const unsigned*)rst)[i];
      oki &= (v <= 1u);
      okf &= (v == 0u || v == 0x3F800000u);
      if ((i & 1) && v != 0u) oddnz = 1;
    }
    if (!oki) atomicAnd(&s_oki, 0);
    if (!okf) atomicAnd(&s_okf, 0);
    if (oddnz) atomicOr(&s_oddnz, 1);
  }

  // ---- load this wave's weight B-fragments into registers (once) ----
  // waves 0-1: W_hh tile wv (cols wv*16+lr); waves 2-3: W_ih tile wv-2
  const float* Wsrc = (wv < 2) ? whh : wih;
  const int nloc = (wv & 1) * 16 + lr;  // local gate col 0..31
  const int growW = (nloc >> 3) * CDIM + cg * 8 + (nloc & 7);
  short8 wfrag[16];
#pragma unroll
  for (int kk = 0; kk < 16; ++kk) {
    const float* s = Wsrc + (size_t)growW * CDIM + kk * 32 + grp * 8;
    float4 lo = *(const float4*)s; float4 hi = *(const float4*)(s + 4);
    wfrag[kk] = pack8(lo, hi);
  }

  if (tid < 32) {
    int grow2 = (tid >> 3) * CDIM + cg * 8 + (tid & 7);
    BIASf[tid] = bih[grow2] + bhh[grow2];
  }
  if (wv >= 2) stage_x(smem, x, 0, bg, tid);
  __syncthreads();
  const int mode = s_oki ? (s_oddnz ? 0 : 3) : (s_okf ? 2 : 1);

  // ---- prologue: xg[0] into XG phase 0 ----
  if (wv >= 2) {
    f32x4 acc = {0.f, 0.f, 0.f, 0.f};
#pragma unroll
    for (int kk = 0; kk < 16; ++kk) {
      int ab = lr * 1024 + ((kk * 64 + grp * 16) ^ ((lr & 7) << 4));
      short8 a = *(const short8*)(smem + XA_OFF + ab);
      acc = __builtin_amdgcn_mfma_f32_16x16x32_bf16(a, wfrag[kk], acc, 0, 0, 0);
    }
#pragma unroll
    for (int q = 0; q < 4; ++q) {
      int m = grp * 4 + q, n = (wv - 2) * 16 + lr;
      XGf[m * 33 + n] = acc[q] + BIASf[n];
    }
  }
  __syncthreads();

  // ---- main sequential loop ----
  for (int t = 0; t < TSTEPS; ++t) {
    const int pcur = t & 1, pnext = pcur ^ 1;

    f32x4 acc = {0.f, 0.f, 0.f, 0.f};
    if (wv < 2) {
      // ---- recurrent path: get h[t-1] (pre-masked) as A-fragments ----
      short8 afrag[16];
      if (t == 0) {
        float kp = keepf(rst, mode, bg * 16 + lr);
#pragma unroll
        for (int kk = 0; kk < 16; ++kk) {
          const float* s = h0 + (size_t)(bg * 16 + lr) * CDIM + kk * 32 + grp * 8;
          float4 lo = *(const float4*)s; float4 hi = *(const float4*)(s + 4);
          lo.x *= kp; lo.y *= kp; lo.z *= kp; lo.w *= kp;
          hi.x *= kp; hi.y *= kp; hi.z *= kp; hi.w *= kp;
          afrag[kk] = pack8(lo, hi);
        }
      } else {
        const unsigned tgt = (unsigned)t;
        while (true) {
          unsigned v = __hip_atomic_load(&flags[bg + 4 * lane], __ATOMIC_RELAXED,
                                         __HIP_MEMORY_SCOPE_AGENT);
          if (__all((int)(v >= tgt))) break;
          __builtin_amdgcn_s_sleep(1);
        }
        asm volatile("" ::: "memory");
        const unsigned long long* hq = (const unsigned long long*)hex;
        const size_t rb = ((size_t)(pnext * 4 + bg) * 8192 + (size_t)lr * 512) >> 2;
#pragma unroll
        for (int kk = 0; kk < 16; ++kk) {
          size_t qi = rb + (size_t)(kk * 8 + grp * 2);
          unsigned long long a0 = __hip_atomic_load(hq + qi, __ATOMIC_RELAXED,
                                                    __HIP_MEMORY_SCOPE_AGENT);
          unsigned long long a1 = __hip_atomic_load(hq + qi + 1, __ATOMIC_RELAXED,
                                                    __HIP_MEMORY_SCOPE_AGENT);
          union { unsigned long long q[2]; short8 s; } uu;
          uu.q[0] = a0; uu.q[1] = a1;
          afrag[kk] = uu.s;
        }
      }
#pragma unroll
      for (int kk = 0; kk < 16; ++kk)
        acc = __builtin_amdgcn_mfma_f32_16x16x32_bf16(afrag[kk], wfrag[kk], acc,
                                                      0, 0, 0);
    } else {
      if (t + 1 < TSTEPS) stage_x(smem, x, t + 1, bg, tid);
    }
    __syncthreads();  // B1

    if (wv < 2) {
      // gates = recurrent + xg[t]
#pragma unroll
      for (int q = 0; q < 4; ++q) {
        int m = grp * 4 + q, n = wv * 16 + lr;
        GBf[m * 33 + n] = acc[q] + XGf[pcur * 528 + m * 33 + n];
      }
    } else if (t + 1 < TSTEPS) {
      // xg[t+1]
      f32x4 xacc = {0.f, 0.f, 0.f, 0.f};
#pragma unroll
      for (int kk = 0; kk < 16; ++kk) {
        int ab = lr * 1024 + ((kk * 64 + grp * 16) ^ ((lr & 7) << 4));
        short8 a = *(const short8*)(smem + XA_OFF + ab);
        xacc = __builtin_amdgcn_mfma_f32_16x16x32_bf16(a, wfrag[kk], xacc, 0, 0, 0);
      }
#pragma unroll
      for (int q = 0; q < 4; ++q) {
        int m = grp * 4 + q, n = (wv - 2) * 16 + lr;
        XGf[pnext * 528 + m * 33 + n] = xacc[q] + BIASf[n];
      }
    }
    __syncthreads();  // B2

    // ---- cell update: wave 0 only (64 threads x 2 c-indices) ----
    if (tid < 64) {
      const int m = tid >> 2, jj0 = (tid & 3) * 2;
      const int cb = m * 8 + jj0;
      float kp = keepf(rst, mode, t * BATCH + bg * 16 + m);
      float ca, cbv;
      if (t == 0) {
        const float* cs = c0 + (size_t)(bg * 16 + m) * CDIM + cg * 8 + jj0;
        ca = cs[0]; cbv = cs[1];
      } else {
        ca = CBf[cb]; cbv = CBf[cb + 1];
      }
      ca *= kp; cbv *= kp;
      float gi0 = GBf[m * 33 + jj0],      gi1 = GBf[m * 33 + jj0 + 1];
      float gf0 = GBf[m * 33 + 8 + jj0],  gf1 = GBf[m * 33 + 8 + jj0 + 1];
      float gg0 = GBf[m * 33 + 16 + jj0], gg1 = GBf[m * 33 + 16 + jj0 + 1];
      float go0 = GBf[m * 33 + 24 + jj0], go1 = GBf[m * 33 + 24 + jj0 + 1];
      float cn0 = sigm(gf0) * ca + sigm(gi0) * tanhf(gg0);
      float cn1 = sigm(gf1) * cbv + sigm(gi1) * tanhf(gg1);
      float hn0 = sigm(go0) * tanhf(cn0);
      float hn1 = sigm(go1) * tanhf(cn1);
      CBf[cb] = cn0; CBf[cb + 1] = cn1;

      if (t + 1 < TSTEPS) {
        // pre-mask with reset[t+1]; store to exchange buffer (sc1 -> MALL)
        float kp1 = keepf(rst, mode, (t + 1) * BATCH + bg * 16 + m);
        unsigned p0 = (kp1 == 0.0f) ? 0u : (unsigned)f2bf(hn0);
        unsigned p1 = (kp1 == 0.0f) ? 0u : (unsigned)f2bf(hn1);
        unsigned pk = p0 | (p1 << 16);
        unsigned* hp = (unsigned*)hex +
                       (((size_t)(pcur * 4 + bg) * 8192 + (size_t)m * 512 +
                         cg * 8 + jj0) >> 1);
        __hip_atomic_store(hp, pk, __ATOMIC_RELAXED, __HIP_MEMORY_SCOPE_AGENT);
        asm volatile("s_waitcnt vmcnt(0)" ::: "memory");  // h visible at MALL
        if (tid == 0)
          __hip_atomic_store(&flags[bid], (unsigned)(t + 1), __ATOMIC_RELAXED,
                             __HIP_MEMORY_SCOPE_AGENT);
      }
      // y store after flag: HBM latency off the critical path
      f32x2 yv; yv[0] = hn0; yv[1] = hn1;
      __builtin_nontemporal_store(
          yv, (f32x2*)&y[((size_t)t * BATCH + bg * 16 + m) * CDIM + cg * 8 + jj0]);
    }
  }
}

extern "C" void kernel_launch(void* const* d_in, const int* in_sizes, int n_in,
                              void* d_out, int out_size, void* d_ws, size_t ws_size,
                              hipStream_t stream) {
  (void)in_sizes; (void)n_in; (void)out_size; (void)ws_size;
  const float* x = (const float*)d_in[0];
  const void* rst = d_in[1];
  const float* h0 = (const float*)d_in[2];
  const float* c0 = (const float*)d_in[3];
  const float* wih = (const float*)d_in[4];
  const float* whh = (const float*)d_in[5];
  const float* bih = (const float*)d_in[6];
  const float* bhh = (const float*)d_in[7];
  float* y = (float*)d_out;
  unsigned short* hex = (unsigned short*)d_ws;
  unsigned* flags = (unsigned*)((char*)d_ws + HEX_BYTES);

  (void)hipMemsetAsync((char*)d_ws + HEX_BYTES, 0, NBLOCKS * sizeof(unsigned),
                       stream);

  (void)hipFuncSetAttribute(reinterpret_cast<const void*>(rlstm_persistent),
                            hipFuncAttributeMaxDynamicSharedMemorySize, SMEM_BYTES);

  void* args[] = {(void*)&x,   (void*)&rst, (void*)&h0,  (void*)&c0,
                  (void*)&wih, (void*)&whh, (void*)&bih, (void*)&bhh,
                  (void*)&y,   (void*)&hex, (void*)&flags};
  (void)hipLaunchCooperativeKernel((void*)rlstm_persistent, dim3(NBLOCKS),
                                   dim3(NTHREADS), args, SMEM_BYTES, stream);
}

// Round 4
// 6101.763 us; speedup vs baseline: 2.6106x; 1.2235x over previous
//
#include <hip/hip_runtime.h>
#include <math.h>

typedef __attribute__((ext_vector_type(8))) short short8;
typedef __attribute__((ext_vector_type(4))) float f32x4;

#define TSTEPS 1024
#define BATCH  64
#define CDIM   512
#define NGATE  2048

// ---- workspace layout ----
#define XG_BYTES ((size_t)TSTEPS * BATCH * NGATE * 2)   // 256 MiB bf16
#define HEX_OFF  XG_BYTES
#define HEX_U16  (2 * 4 * 16 * 512)                      // [phase][bg][row][c]
#define FLAG_OFF (HEX_OFF + (size_t)HEX_U16 * 2)
#define WS_NEED  (FLAG_OFF + 64 * 4)

// ---- sequential kernel geometry: 64 blocks (4 bg x 16 cg) x 512 thr ----
#define SEQ_BLOCKS  64
#define SEQ_THREADS 512
#define SMEM_BYTES  98304   // pad to force 1 block/CU
#define HA_OFF 0            // 16 x 512 bf16 swizzled = 16384
#define RM_OFF 16384        // 1024 u64 reset bitmask = 8192

__device__ __forceinline__ unsigned short f2bf(float x) {
  unsigned u = __builtin_bit_cast(unsigned, x);
  unsigned r = (u + 0x7FFFu + ((u >> 16) & 1u)) >> 16;
  return (unsigned short)r;
}
__device__ __forceinline__ float bf2f(unsigned short b) {
  unsigned u = ((unsigned)b) << 16;
  return __builtin_bit_cast(float, u);
}
__device__ __forceinline__ short8 pack8(float4 lo, float4 hi) {
  short8 r;
  r[0] = (short)f2bf(lo.x); r[1] = (short)f2bf(lo.y);
  r[2] = (short)f2bf(lo.z); r[3] = (short)f2bf(lo.w);
  r[4] = (short)f2bf(hi.x); r[5] = (short)f2bf(hi.y);
  r[6] = (short)f2bf(hi.z); r[7] = (short)f2bf(hi.w);
  return r;
}
__device__ __forceinline__ float sigm(float z) { return 1.0f / (1.0f + expf(-z)); }

// ============ kernel 1: xg[t,b,n] = x[t,b,:]@W_ih[n,:] + bih[n]+bhh[n] ======
// M = 65536 (t*64+b), N = 2048, K = 512. 128x128 tile, BK=64, 4 waves.
__global__ __launch_bounds__(256, 2) void xg_prepass(
    const float* __restrict__ x, const float* __restrict__ wih,
    const float* __restrict__ bih, const float* __restrict__ bhh,
    unsigned short* __restrict__ xg) {
  __shared__ __align__(16) char lds[32768];
  char* Al = lds;
  char* Bl = lds + 16384;
  const int tid = threadIdx.x;
  const int bid = blockIdx.x;
  const int bm = bid & 511, bn = bid >> 9;
  const int lane = tid & 63, wv = tid >> 6;
  const int wm = wv >> 1, wn = wv & 1;
  const int grp = lane >> 4, lr = lane & 15;

  f32x4 acc[4][4] = {};
  float bsum[4];
#pragma unroll
  for (int nt = 0; nt < 4; ++nt) {
    int n = bn * 128 + wn * 64 + nt * 16 + lr;
    bsum[nt] = bih[n] + bhh[n];
  }

  for (int kb = 0; kb < 8; ++kb) {
    __syncthreads();
#pragma unroll
    for (int c = 0; c < 4; ++c) {
      int gi = tid + c * 256;           // 0..1023
      int row = gi >> 3, colc = (gi & 7) * 8;
      const float* sA = x + ((size_t)(bm * 128 + row)) * 512 + kb * 64 + colc;
      float4 lo = *(const float4*)sA, hi = *(const float4*)(sA + 4);
      *(short8*)(Al + row * 128 + ((colc * 2) ^ ((row & 7) << 4))) = pack8(lo, hi);
      const float* sB = wih + ((size_t)(bn * 128 + row)) * 512 + kb * 64 + colc;
      float4 lo2 = *(const float4*)sB, hi2 = *(const float4*)(sB + 4);
      *(short8*)(Bl + row * 128 + ((colc * 2) ^ ((row & 7) << 4))) = pack8(lo2, hi2);
    }
    __syncthreads();
#pragma unroll
    for (int kk = 0; kk < 2; ++kk) {
      short8 af[4], bf[4];
#pragma unroll
      for (int mt = 0; mt < 4; ++mt) {
        int r = wm * 64 + mt * 16 + lr;
        af[mt] = *(const short8*)(Al + r * 128 + ((kk * 64 + grp * 16) ^ ((r & 7) << 4)));
      }
#pragma unroll
      for (int nt = 0; nt < 4; ++nt) {
        int r = wn * 64 + nt * 16 + lr;
        bf[nt] = *(const short8*)(Bl + r * 128 + ((kk * 64 + grp * 16) ^ ((r & 7) << 4)));
      }
#pragma unroll
      for (int mt = 0; mt < 4; ++mt)
#pragma unroll
        for (int nt = 0; nt < 4; ++nt)
          acc[mt][nt] = __builtin_amdgcn_mfma_f32_16x16x32_bf16(af[mt], bf[nt],
                                                                acc[mt][nt], 0, 0, 0);
    }
  }
#pragma unroll
  for (int mt = 0; mt < 4; ++mt)
#pragma unroll
    for (int nt = 0; nt < 4; ++nt)
#pragma unroll
      for (int q = 0; q < 4; ++q) {
        int m = bm * 128 + wm * 64 + mt * 16 + grp * 4 + q;
        int n = bn * 128 + wn * 64 + nt * 16 + lr;
        xg[(size_t)m * NGATE + n] = f2bf(acc[mt][nt][q] + bsum[nt]);
      }
}

// ============ kernel 2: persistent sequential LSTM ==========================
__global__ __launch_bounds__(SEQ_THREADS, 1) void rlstm_seq(
    const void* __restrict__ rst, const float* __restrict__ h0,
    const float* __restrict__ c0, const float* __restrict__ whh,
    float* __restrict__ y, const unsigned short* __restrict__ xg,
    unsigned short* __restrict__ hex, unsigned* __restrict__ flags) {
  extern __shared__ __align__(16) char smem[];
  unsigned long long* RM = (unsigned long long*)(smem + RM_OFF);

  const int tid = threadIdx.x;
  const int bid = blockIdx.x;
  const int bg = bid >> 4;    // batch group (16 batches)
  const int cg = bid & 15;    // 32 c-indices per block
  const int lane = tid & 63;
  const int wv = tid >> 6;    // 8 waves
  const int grp = lane >> 4;  // k-group / m-subrange
  const int lr = lane & 15;
  const int g = lr >> 2;      // gate 0..3 (i,f,g,o)
  const int j = lr & 3;       // c sub-index
  const int cglob = cg * 32 + wv * 4 + j;
  const int nglob = g * CDIM + cglob;   // gate-matrix row

  // ---- detect reset dtype (i32 / u8 / f32 / i64) ----
  __shared__ int s_oki, s_okf, s_oddnz;
  if (tid == 0) { s_oki = 1; s_okf = 1; s_oddnz = 0; }
  __syncthreads();
  {
    int oki = 1, okf = 1, oddnz = 0;
    for (int i = tid; i < 1024; i += SEQ_THREADS) {
      unsigned v = ((const unsigned*)rst)[i];
      oki &= (v <= 1u);
      okf &= (v == 0u || v == 0x3F800000u);
      if ((i & 1) && v != 0u) oddnz = 1;
    }
    if (!oki) atomicAnd(&s_oki, 0);
    if (!okf) atomicAnd(&s_okf, 0);
    if (oddnz) atomicOr(&s_oddnz, 1);
  }
  __syncthreads();
  const int mode = s_oki ? (s_oddnz ? 0 : 3) : (s_okf ? 2 : 1);

  // ---- build reset bitmask in LDS: RM[t] bit b = reset[t][b] ----
  for (int tt = wv; tt < TSTEPS; tt += 8) {
    int idx = tt * BATCH + lane;
    bool r;
    if (mode == 0)      r = ((const int*)rst)[idx] != 0;
    else if (mode == 1) r = ((const unsigned char*)rst)[idx] != 0;
    else if (mode == 2) r = ((const float*)rst)[idx] != 0.0f;
    else                r = ((const int*)rst)[2 * idx] != 0;
    unsigned long long bm = __ballot((int)r);
    if (lane == 0) RM[tt] = bm;
  }

  // ---- W_hh B-fragments into registers (16 cols per wave, permuted) ----
  short8 wfrag[16];
#pragma unroll
  for (int kk = 0; kk < 16; ++kk) {
    const float* s = whh + (size_t)nglob * CDIM + kk * 32 + grp * 8;
    float4 lo = *(const float4*)s, hi = *(const float4*)(s + 4);
    wfrag[kk] = pack8(lo, hi);
  }
  __syncthreads();  // RM ready

  // ---- xg for step 0 ----
  unsigned short xgc[4];
#pragma unroll
  for (int q = 0; q < 4; ++q)
    xgc[q] = xg[((size_t)(bg * 16 + grp * 4 + q)) * NGATE + nglob];

  float cReg[4] = {0.f, 0.f, 0.f, 0.f};

  for (int t = 0; t < TSTEPS; ++t) {
    const int pcur = t & 1, pnext = pcur ^ 1;

    if (t > 0) {
      const unsigned tgt = (unsigned)t;
      while (true) {
        unsigned v = __hip_atomic_load(&flags[bg * 16 + (lane & 15)],
                                       __ATOMIC_RELAXED, __HIP_MEMORY_SCOPE_AGENT);
        if (__all((int)(v >= tgt))) break;
        __builtin_amdgcn_s_sleep(2);
      }
      asm volatile("" ::: "memory");
    }

    // ---- stage h[t-1] (pre-masked by producer) into LDS: waves 0..3 ----
    if (wv < 4) {
      const int row = 4 * wv + (lane >> 4);
      if (t == 0) {
        float kp0 = ((RM[0] >> (bg * 16 + row)) & 1ull) ? 0.f : 1.f;
#pragma unroll
        for (int i = 0; i < 4; ++i) {
          int p = (lane & 15) + i * 16;   // 16B chunk 0..63
          const float* s = h0 + (size_t)(bg * 16 + row) * CDIM + p * 8;
          float4 lo = *(const float4*)s, hi = *(const float4*)(s + 4);
          lo.x *= kp0; lo.y *= kp0; lo.z *= kp0; lo.w *= kp0;
          hi.x *= kp0; hi.y *= kp0; hi.z *= kp0; hi.w *= kp0;
          *(short8*)(smem + HA_OFF + row * 1024 + ((p * 16) ^ ((row & 7) << 4))) =
              pack8(lo, hi);
        }
      } else {
        const unsigned long long* hq =
            (const unsigned long long*)(hex + (size_t)((pnext * 4 + bg) * 16 + row) * 512);
#pragma unroll
        for (int i = 0; i < 4; ++i) {
          int p = (lane & 15) + i * 16;
          unsigned long long a0 = __hip_atomic_load(hq + p * 2, __ATOMIC_RELAXED,
                                                    __HIP_MEMORY_SCOPE_AGENT);
          unsigned long long a1 = __hip_atomic_load(hq + p * 2 + 1, __ATOMIC_RELAXED,
                                                    __HIP_MEMORY_SCOPE_AGENT);
          union { unsigned long long q[2]; short8 s; } uu;
          uu.q[0] = a0; uu.q[1] = a1;
          *(short8*)(smem + HA_OFF + row * 1024 + ((p * 16) ^ ((row & 7) << 4))) = uu.s;
        }
      }
    }
    __syncthreads();  // B1: hA ready

    // prefetch next step's xg slice (consumed next iteration)
    const int tn = (t + 1 < TSTEPS) ? t + 1 : t;
    unsigned short xgn[4];
#pragma unroll
    for (int q = 0; q < 4; ++q)
      xgn[q] = xg[((size_t)tn * BATCH + bg * 16 + grp * 4 + q) * NGATE + nglob];

    // ---- recurrent GEMM: 16x16 tile over K=512 ----
    f32x4 acc = {0.f, 0.f, 0.f, 0.f};
#pragma unroll
    for (int kk = 0; kk < 16; ++kk) {
      short8 a = *(const short8*)(smem + HA_OFF + lr * 1024 +
                                  ((kk * 64 + grp * 16) ^ ((lr & 7) << 4)));
      acc = __builtin_amdgcn_mfma_f32_16x16x32_bf16(a, wfrag[kk], acc, 0, 0, 0);
    }

    // ---- in-register cell: butterfly transpose of gate quadrants ----
    const unsigned long long kw = RM[t];
    const unsigned long long kw1 = RM[tn];
    float hsel = 0.f;
#pragma unroll
    for (int q = 0; q < 4; ++q) {
      float v0 = acc[q] + bf2f(xgc[q]);
      float ex1 = __shfl_xor(v0, 4);
      float a = (g & 1) ? ex1 : v0;
      float b = (g & 1) ? v0 : ex1;
      float exA = __shfl_xor(a, 8);
      float exB = __shfl_xor(b, 8);
      float gi = (g & 2) ? exA : a;
      float gf = (g & 2) ? exB : b;
      float gg = (g & 2) ? a : exA;
      float go = (g & 2) ? b : exB;
      int m = grp * 4 + q;
      float kp = ((kw >> (bg * 16 + m)) & 1ull) ? 0.f : 1.f;
      float cprev = (t == 0) ? c0[(size_t)(bg * 16 + m) * CDIM + cglob] : cReg[q];
      cprev *= kp;
      float cn = sigm(gf) * cprev + sigm(gi) * tanhf(gg);
      cReg[q] = cn;
      if (q == g) hsel = sigm(go) * tanhf(cn);
    }

    // ---- store h slice (pre-masked with reset[t+1]) to exchange buffer ----
    const int msel = grp * 4 + g;
    if (t + 1 < TSTEPS) {
      bool r1 = (kw1 >> (bg * 16 + msel)) & 1ull;
      unsigned short hb = r1 ? (unsigned short)0 : f2bf(hsel);
      __hip_atomic_store(hex + (size_t)((pcur * 4 + bg) * 16 + msel) * 512 + cglob,
                         hb, __ATOMIC_RELAXED, __HIP_MEMORY_SCOPE_AGENT);
    }
    asm volatile("s_waitcnt vmcnt(0)" ::: "memory");  // h at coherence point
    __syncthreads();  // B2: all waves' h stores drained
    if (tid == 0 && t + 1 < TSTEPS)
      __hip_atomic_store(&flags[bid], (unsigned)(t + 1), __ATOMIC_RELAXED,
                         __HIP_MEMORY_SCOPE_AGENT);

    // y store off the critical path
    y[((size_t)t * BATCH + bg * 16 + msel) * CDIM + cglob] = hsel;

#pragma unroll
    for (int q = 0; q < 4; ++q) xgc[q] = xgn[q];
  }
}

extern "C" void kernel_launch(void* const* d_in, const int* in_sizes, int n_in,
                              void* d_out, int out_size, void* d_ws, size_t ws_size,
                              hipStream_t stream) {
  (void)in_sizes; (void)n_in; (void)out_size;
  const float* x = (const float*)d_in[0];
  const void* rstp = (const void*)d_in[1];
  const float* h0 = (const float*)d_in[2];
  const float* c0 = (const float*)d_in[3];
  const float* wih = (const float*)d_in[4];
  const float* whh = (const float*)d_in[5];
  const float* bih = (const float*)d_in[6];
  const float* bhh = (const float*)d_in[7];
  float* y = (float*)d_out;

  if (ws_size < WS_NEED) return;  // diagnosable clean failure

  unsigned short* xgp = (unsigned short*)d_ws;
  unsigned short* hex = (unsigned short*)((char*)d_ws + HEX_OFF);
  unsigned* flags = (unsigned*)((char*)d_ws + FLAG_OFF);

  (void)hipMemsetAsync((char*)d_ws + FLAG_OFF, 0, 64 * sizeof(unsigned), stream);

  // pre-pass: xg = x @ W_ih^T + bih + bhh   (8192 blocks: 512 bm x 16 bn)
  xg_prepass<<<dim3(8192), dim3(256), 0, stream>>>(x, wih, bih, bhh, xgp);

  (void)hipFuncSetAttribute(reinterpret_cast<const void*>(rlstm_seq),
                            hipFuncAttributeMaxDynamicSharedMemorySize, SMEM_BYTES);
  void* args[] = {(void*)&rstp, (void*)&h0, (void*)&c0, (void*)&whh,
                  (void*)&y,    (void*)&xgp, (void*)&hex, (void*)&flags};
  (void)hipLaunchCooperativeKernel((void*)rlstm_seq, dim3(SEQ_BLOCKS),
                                   dim3(SEQ_THREADS), args, SMEM_BYTES, stream);
}

// Round 5
// 5703.154 us; speedup vs baseline: 2.7931x; 1.0699x over previous
//
#include <hip/hip_runtime.h>
#include <math.h>

typedef __attribute__((ext_vector_type(8))) short short8;
typedef __attribute__((ext_vector_type(4))) float f32x4;

#define TSTEPS 1024
#define BATCH  64
#define CDIM   512
#define NGATE  2048

// ---- workspace layout ----
#define XG_BYTES ((size_t)TSTEPS * BATCH * NGATE * 2)   // 256 MiB bf16
#define HEX_OFF  XG_BYTES
// hex: u32 [phase][bg][row][c] tagged words = 2*4*16*512*4 = 256 KiB
#define HEX_BYTES (2 * 4 * 16 * 512 * 4)
#define WS_NEED  (HEX_OFF + HEX_BYTES)

// ---- sequential kernel geometry: 64 blocks (4 bg x 16 cg) x 512 thr ----
#define SEQ_BLOCKS  64
#define SEQ_THREADS 512
#define SMEM_BYTES  98304   // pad to force 1 block/CU
#define HA_OFF 0            // 2 x (16 x 512 bf16 swizzled) = 32768 (double buffer)
#define RM_OFF 32768        // 1024 u64 reset bitmask = 8192

__device__ __forceinline__ unsigned short f2bf(float x) {
  unsigned u = __builtin_bit_cast(unsigned, x);
  unsigned r = (u + 0x7FFFu + ((u >> 16) & 1u)) >> 16;
  return (unsigned short)r;
}
__device__ __forceinline__ float bf2f(unsigned short b) {
  unsigned u = ((unsigned)b) << 16;
  return __builtin_bit_cast(float, u);
}
__device__ __forceinline__ short8 pack8(float4 lo, float4 hi) {
  short8 r;
  r[0] = (short)f2bf(lo.x); r[1] = (short)f2bf(lo.y);
  r[2] = (short)f2bf(lo.z); r[3] = (short)f2bf(lo.w);
  r[4] = (short)f2bf(hi.x); r[5] = (short)f2bf(hi.y);
  r[6] = (short)f2bf(hi.z); r[7] = (short)f2bf(hi.w);
  return r;
}
__device__ __forceinline__ float sigm(float z) { return 1.0f / (1.0f + expf(-z)); }

// ============ kernel 1: xg[t,b,n] = x[t,b,:]@W_ih[n,:] + bih[n]+bhh[n] ======
// M = 65536 (t*64+b), N = 2048, K = 512. 128x128 tile, BK=64, 4 waves.
__global__ __launch_bounds__(256, 2) void xg_prepass(
    const float* __restrict__ x, const float* __restrict__ wih,
    const float* __restrict__ bih, const float* __restrict__ bhh,
    unsigned short* __restrict__ xg) {
  __shared__ __align__(16) char lds[32768];
  char* Al = lds;
  char* Bl = lds + 16384;
  const int tid = threadIdx.x;
  const int bid = blockIdx.x;
  const int bm = bid & 511, bn = bid >> 9;
  const int lane = tid & 63, wv = tid >> 6;
  const int wm = wv >> 1, wn = wv & 1;
  const int grp = lane >> 4, lr = lane & 15;

  f32x4 acc[4][4] = {};
  float bsum[4];
#pragma unroll
  for (int nt = 0; nt < 4; ++nt) {
    int n = bn * 128 + wn * 64 + nt * 16 + lr;
    bsum[nt] = bih[n] + bhh[n];
  }

  for (int kb = 0; kb < 8; ++kb) {
    __syncthreads();
#pragma unroll
    for (int c = 0; c < 4; ++c) {
      int gi = tid + c * 256;           // 0..1023
      int row = gi >> 3, colc = (gi & 7) * 8;
      const float* sA = x + ((size_t)(bm * 128 + row)) * 512 + kb * 64 + colc;
      float4 lo = *(const float4*)sA, hi = *(const float4*)(sA + 4);
      *(short8*)(Al + row * 128 + ((colc * 2) ^ ((row & 7) << 4))) = pack8(lo, hi);
      const float* sB = wih + ((size_t)(bn * 128 + row)) * 512 + kb * 64 + colc;
      float4 lo2 = *(const float4*)sB, hi2 = *(const float4*)(sB + 4);
      *(short8*)(Bl + row * 128 + ((colc * 2) ^ ((row & 7) << 4))) = pack8(lo2, hi2);
    }
    __syncthreads();
#pragma unroll
    for (int kk = 0; kk < 2; ++kk) {
      short8 af[4], bf[4];
#pragma unroll
      for (int mt = 0; mt < 4; ++mt) {
        int r = wm * 64 + mt * 16 + lr;
        af[mt] = *(const short8*)(Al + r * 128 + ((kk * 64 + grp * 16) ^ ((r & 7) << 4)));
      }
#pragma unroll
      for (int nt = 0; nt < 4; ++nt) {
        int r = wn * 64 + nt * 16 + lr;
        bf[nt] = *(const short8*)(Bl + r * 128 + ((kk * 64 + grp * 16) ^ ((r & 7) << 4)));
      }
#pragma unroll
      for (int mt = 0; mt < 4; ++mt)
#pragma unroll
        for (int nt = 0; nt < 4; ++nt)
          acc[mt][nt] = __builtin_amdgcn_mfma_f32_16x16x32_bf16(af[mt], bf[nt],
                                                                acc[mt][nt], 0, 0, 0);
    }
  }
#pragma unroll
  for (int mt = 0; mt < 4; ++mt)
#pragma unroll
    for (int nt = 0; nt < 4; ++nt)
#pragma unroll
      for (int q = 0; q < 4; ++q) {
        int m = bm * 128 + wm * 64 + mt * 16 + grp * 4 + q;
        int n = bn * 128 + wn * 64 + nt * 16 + lr;
        xg[(size_t)m * NGATE + n] = f2bf(acc[mt][nt][q] + bsum[nt]);
      }
}

// ============ kernel 2: persistent sequential LSTM ==========================
// h exchange word: (h_bf16 << 16) | step_tag. Tag match => payload valid.
__global__ __launch_bounds__(SEQ_THREADS, 1) void rlstm_seq(
    const void* __restrict__ rst, const float* __restrict__ h0,
    const float* __restrict__ c0, const float* __restrict__ whh,
    float* __restrict__ y, const unsigned short* __restrict__ xg,
    unsigned* __restrict__ hex) {
  extern __shared__ __align__(16) char smem[];
  unsigned long long* RM = (unsigned long long*)(smem + RM_OFF);

  const int tid = threadIdx.x;
  const int bid = blockIdx.x;
  const int bg = bid >> 4;    // batch group (16 batches)
  const int cg = bid & 15;    // 32 c-indices per block
  const int lane = tid & 63;
  const int wv = tid >> 6;    // 8 waves
  const int grp = lane >> 4;  // k-group / m-subrange
  const int lr = lane & 15;
  const int g = lr >> 2;      // gate 0..3 (i,f,g,o)
  const int j = lr & 3;       // c sub-index
  const int cglob = cg * 32 + wv * 4 + j;
  const int nglob = g * CDIM + cglob;   // gate-matrix row

  // ---- detect reset dtype (i32 / u8 / f32 / i64) ----
  __shared__ int s_oki, s_okf, s_oddnz;
  if (tid == 0) { s_oki = 1; s_okf = 1; s_oddnz = 0; }
  __syncthreads();
  {
    int oki = 1, okf = 1, oddnz = 0;
    for (int i = tid; i < 1024; i += SEQ_THREADS) {
      unsigned v = ((const unsigned*)rst)[i];
      oki &= (v <= 1u);
      okf &= (v == 0u || v == 0x3F800000u);
      if ((i & 1) && v != 0u) oddnz = 1;
    }
    if (!oki) atomicAnd(&s_oki, 0);
    if (!okf) atomicAnd(&s_okf, 0);
    if (oddnz) atomicOr(&s_oddnz, 1);
  }
  __syncthreads();
  const int mode = s_oki ? (s_oddnz ? 0 : 3) : (s_okf ? 2 : 1);

  // ---- build reset bitmask in LDS: RM[t] bit b = reset[t][b] ----
  for (int tt = wv; tt < TSTEPS; tt += 8) {
    int idx = tt * BATCH + lane;
    bool r;
    if (mode == 0)      r = ((const int*)rst)[idx] != 0;
    else if (mode == 1) r = ((const unsigned char*)rst)[idx] != 0;
    else if (mode == 2) r = ((const float*)rst)[idx] != 0.0f;
    else                r = ((const int*)rst)[2 * idx] != 0;
    unsigned long long bm = __ballot((int)r);
    if (lane == 0) RM[tt] = bm;
  }

  // ---- W_hh B-fragments into registers (16 cols per wave, permuted) ----
  short8 wfrag[16];
#pragma unroll
  for (int kk = 0; kk < 16; ++kk) {
    const float* s = whh + (size_t)nglob * CDIM + kk * 32 + grp * 8;
    float4 lo = *(const float4*)s, hi = *(const float4*)(s + 4);
    wfrag[kk] = pack8(lo, hi);
  }
  __syncthreads();  // RM ready

  // ---- xg for step 0 ----
  unsigned short xgc[4];
#pragma unroll
  for (int q = 0; q < 4; ++q)
    xgc[q] = xg[((size_t)(bg * 16 + grp * 4 + q)) * NGATE + nglob];

  float cReg[4] = {0.f, 0.f, 0.f, 0.f};

  // staging geometry: each wave stages 2 rows; 32 lanes per row
  const int srow = 2 * wv + (lane >> 5);
  const int wcol = lane & 31;

  for (int t = 0; t < TSTEPS; ++t) {
    const int pcur = t & 1, pnext = pcur ^ 1;
    char* habuf = smem + HA_OFF + pcur * 16384;

    // prefetch next step's xg slice early (latency hides under poll)
    const int tn = (t + 1 < TSTEPS) ? t + 1 : t;
    unsigned short xgn[4];
#pragma unroll
    for (int q = 0; q < 4; ++q)
      xgn[q] = xg[((size_t)tn * BATCH + bg * 16 + grp * 4 + q) * NGATE + nglob];

    // ---- stage h[t-1] into LDS (self-certifying tagged words) ----
    if (t == 0) {
      float kp0 = ((RM[0] >> (bg * 16 + srow)) & 1ull) ? 0.f : 1.f;
#pragma unroll
      for (int i = 0; i < 2; ++i) {
        int p = wcol + 32 * i;          // 16B chunk 0..63
        const float* s = h0 + (size_t)(bg * 16 + srow) * CDIM + p * 8;
        float4 lo = *(const float4*)s, hi = *(const float4*)(s + 4);
        lo.x *= kp0; lo.y *= kp0; lo.z *= kp0; lo.w *= kp0;
        hi.x *= kp0; hi.y *= kp0; hi.z *= kp0; hi.w *= kp0;
        *(short8*)(habuf + srow * 1024 + ((p * 16) ^ ((srow & 7) << 4))) =
            pack8(lo, hi);
      }
    } else {
      const unsigned long long* hq =
          (const unsigned long long*)(hex +
                                      (size_t)((pnext * 4 + bg) * 16 + srow) * 512);
      const unsigned tagexp = (unsigned)t;
      unsigned long long vals[8];
      unsigned pend = 0xffu;
      do {
#pragma unroll
        for (int i = 0; i < 8; ++i)
          if (pend & (1u << i))
            vals[i] = __hip_atomic_load(hq + wcol + 32 * i, __ATOMIC_RELAXED,
                                        __HIP_MEMORY_SCOPE_AGENT);
        unsigned np = 0;
#pragma unroll
        for (int i = 0; i < 8; ++i) {
          unsigned lo = (unsigned)vals[i];
          unsigned hi = (unsigned)(vals[i] >> 32);
          if (((lo & 0xffffu) != tagexp) || ((hi & 0xffffu) != tagexp))
            np |= 1u << i;
        }
        pend = np;
      } while (__any((int)pend));
#pragma unroll
      for (int i = 0; i < 8; ++i) {
        int w = wcol + 32 * i;
        unsigned lo = (unsigned)vals[i];
        unsigned hi = (unsigned)(vals[i] >> 32);
        unsigned pk = (lo >> 16) | (hi & 0xffff0000u);
        *(unsigned*)(habuf + srow * 1024 + ((w * 4) ^ ((srow & 7) << 4))) = pk;
      }
    }
    __syncthreads();  // the ONLY barrier per step

    // ---- recurrent GEMM: 16x16 tile over K=512 ----
    f32x4 acc = {0.f, 0.f, 0.f, 0.f};
#pragma unroll
    for (int kk = 0; kk < 16; ++kk) {
      short8 a = *(const short8*)(habuf + lr * 1024 +
                                  ((kk * 64 + grp * 16) ^ ((lr & 7) << 4)));
      acc = __builtin_amdgcn_mfma_f32_16x16x32_bf16(a, wfrag[kk], acc, 0, 0, 0);
    }

    // ---- in-register cell: butterfly transpose of gate quadrants ----
    const unsigned long long kw = RM[t];
    const unsigned long long kw1 = RM[tn];
    float hsel = 0.f;
#pragma unroll
    for (int q = 0; q < 4; ++q) {
      float v0 = acc[q] + bf2f(xgc[q]);
      float ex1 = __shfl_xor(v0, 4);
      float a = (g & 1) ? ex1 : v0;
      float b = (g & 1) ? v0 : ex1;
      float exA = __shfl_xor(a, 8);
      float exB = __shfl_xor(b, 8);
      float gi = (g & 2) ? exA : a;
      float gf = (g & 2) ? exB : b;
      float gg = (g & 2) ? a : exA;
      float go = (g & 2) ? b : exB;
      int m = grp * 4 + q;
      float kp = ((kw >> (bg * 16 + m)) & 1ull) ? 0.f : 1.f;
      float cprev = (t == 0) ? c0[(size_t)(bg * 16 + m) * CDIM + cglob] : cReg[q];
      cprev *= kp;
      float cn = sigm(gf) * cprev + sigm(gi) * tanhf(gg);
      cReg[q] = cn;
      if (q == g) hsel = sigm(go) * tanhf(cn);
    }

    // ---- fire-and-forget tagged h store (pre-masked with reset[t+1]) ----
    const int msel = grp * 4 + g;
    if (t + 1 < TSTEPS) {
      bool r1 = (kw1 >> (bg * 16 + msel)) & 1ull;
      unsigned short hb = r1 ? (unsigned short)0 : f2bf(hsel);
      unsigned word = ((unsigned)hb << 16) | (unsigned)(t + 1);
      __hip_atomic_store(hex + (size_t)((pcur * 4 + bg) * 16 + msel) * 512 + cglob,
                         word, __ATOMIC_RELAXED, __HIP_MEMORY_SCOPE_AGENT);
    }

    // y store off the critical path
    y[((size_t)t * BATCH + bg * 16 + msel) * CDIM + cglob] = hsel;

#pragma unroll
    for (int q = 0; q < 4; ++q) xgc[q] = xgn[q];
  }
}

extern "C" void kernel_launch(void* const* d_in, const int* in_sizes, int n_in,
                              void* d_out, int out_size, void* d_ws, size_t ws_size,
                              hipStream_t stream) {
  (void)in_sizes; (void)n_in; (void)out_size;
  const float* x = (const float*)d_in[0];
  const void* rstp = (const void*)d_in[1];
  const float* h0 = (const float*)d_in[2];
  const float* c0 = (const float*)d_in[3];
  const float* wih = (const float*)d_in[4];
  const float* whh = (const float*)d_in[5];
  const float* bih = (const float*)d_in[6];
  const float* bhh = (const float*)d_in[7];
  float* y = (float*)d_out;

  if (ws_size < WS_NEED) return;  // diagnosable clean failure

  unsigned short* xgp = (unsigned short*)d_ws;
  unsigned* hex = (unsigned*)((char*)d_ws + HEX_OFF);

  // clear tags (stale tags from a previous graph replay would alias at t=1023)
  (void)hipMemsetAsync((char*)d_ws + HEX_OFF, 0, HEX_BYTES, stream);

  // pre-pass: xg = x @ W_ih^T + bih + bhh   (8192 blocks: 512 bm x 16 bn)
  xg_prepass<<<dim3(8192), dim3(256), 0, stream>>>(x, wih, bih, bhh, xgp);

  (void)hipFuncSetAttribute(reinterpret_cast<const void*>(rlstm_seq),
                            hipFuncAttributeMaxDynamicSharedMemorySize, SMEM_BYTES);
  void* args[] = {(void*)&rstp, (void*)&h0, (void*)&c0, (void*)&whh,
                  (void*)&y,    (void*)&xgp, (void*)&hex};
  (void)hipLaunchCooperativeKernel((void*)rlstm_seq, dim3(SEQ_BLOCKS),
                                   dim3(SEQ_THREADS), args, SMEM_BYTES, stream);
}